// Round 4
// baseline (23124.300 us; speedup 1.0000x reference)
//
#include <hip/hip_runtime.h>
#include <math.h>

#define B_   64
#define T_   366
#define IN_  24
#define H1_  1024
#define H2_  2048
#define HM_  2048
#define G3_  (3 * HM_)
#define PEN_ 1024
#define C_   21
#define BT_  (B_ * T_)

#define TC_  61              // T-chunk length (366 = 6*61)
#define NCH  6
#define MC   (B_ * TC_)      // 3904 rows per chunk

#define BM 64
#define BN 64
#define BKK 16
#define KC 256               // K-chunk for recurrence split-K

typedef unsigned short bf16_t;

__device__ __forceinline__ float bf2f(bf16_t u) {
  return __uint_as_float(((unsigned int)u) << 16);
}
__device__ __forceinline__ bf16_t f2bf(float f) {
  unsigned int x = __float_as_uint(f);
  unsigned int r = (x + 0x7fffu + ((x >> 16) & 1u)) >> 16;
  return (bf16_t)r;
}
__device__ __forceinline__ float bf2f_or_id(float f) { return f; }
__device__ __forceinline__ float bf2f_or_id(bf16_t u) { return bf2f(u); }

struct ushort4_t { bf16_t x, y, z, w; };

// ---------------------------------------------------------------------------
// Generic tiled GEMM: C[m,n] = act(sum_k A[m,k]*W[n,k] + bias[n])
// A: MxK row-major (fp32 or bf16); W: NxK fp32; C fp32 or bf16. M,N,K mult of tile.
// ---------------------------------------------------------------------------
template <typename TA, typename TC>
__global__ __launch_bounds__(256) void gemm_nt(
    const TA* __restrict__ A, const float* __restrict__ W,
    const float* __restrict__ bias, TC* __restrict__ C,
    int M, int N, int K, int relu)
{
  __shared__ float As[BKK][BM];
  __shared__ float Ws[BKK][BN];
  const int tid = threadIdx.x;
  const int m0 = blockIdx.x * BM;
  const int n0 = blockIdx.y * BN;
  const int lr = tid >> 2;
  const int kq = (tid & 3) << 2;
  const int ty = tid >> 4;
  const int tx = tid & 15;
  float acc[4][4] = {};
  for (int k0 = 0; k0 < K; k0 += BKK) {
    {
      float v0, v1, v2, v3;
      if constexpr (sizeof(TA) == 4) {
        const float4 v = *(const float4*)((const float*)A + (size_t)(m0 + lr) * K + (k0 + kq));
        v0 = v.x; v1 = v.y; v2 = v.z; v3 = v.w;
      } else {
        const ushort4_t v = *(const ushort4_t*)((const bf16_t*)A + (size_t)(m0 + lr) * K + (k0 + kq));
        v0 = bf2f(v.x); v1 = bf2f(v.y); v2 = bf2f(v.z); v3 = bf2f(v.w);
      }
      As[kq + 0][lr] = v0; As[kq + 1][lr] = v1;
      As[kq + 2][lr] = v2; As[kq + 3][lr] = v3;
      const float4 w = *(const float4*)(W + (size_t)(n0 + lr) * K + (k0 + kq));
      Ws[kq + 0][lr] = w.x; Ws[kq + 1][lr] = w.y;
      Ws[kq + 2][lr] = w.z; Ws[kq + 3][lr] = w.w;
    }
    __syncthreads();
    #pragma unroll
    for (int k = 0; k < BKK; ++k) {
      const float4 av = *(const float4*)&As[k][ty << 2];
      const float4 bv = *(const float4*)&Ws[k][tx << 2];
      const float aa[4] = {av.x, av.y, av.z, av.w};
      const float bb[4] = {bv.x, bv.y, bv.z, bv.w};
      #pragma unroll
      for (int i = 0; i < 4; ++i)
        #pragma unroll
        for (int j = 0; j < 4; ++j)
          acc[i][j] = fmaf(aa[i], bb[j], acc[i][j]);
    }
    __syncthreads();
  }
  const float4 bvec = *(const float4*)&bias[n0 + (tx << 2)];
  const float bb[4] = {bvec.x, bvec.y, bvec.z, bvec.w};
  #pragma unroll
  for (int i = 0; i < 4; ++i) {
    float o[4];
    #pragma unroll
    for (int j = 0; j < 4; ++j) {
      o[j] = acc[i][j] + bb[j];
      if (relu) o[j] = fmaxf(o[j], 0.f);
    }
    if constexpr (sizeof(TC) == 4) {
      float4 ov = {o[0], o[1], o[2], o[3]};
      *(float4*)((float*)C + (size_t)(m0 + (ty << 2) + i) * N + n0 + (tx << 2)) = ov;
    } else {
      ushort4_t ov = {f2bf(o[0]), f2bf(o[1]), f2bf(o[2]), f2bf(o[3])};
      *(ushort4_t*)((bf16_t*)C + (size_t)(m0 + (ty << 2) + i) * N + n0 + (tx << 2)) = ov;
    }
  }
}

// ---------------------------------------------------------------------------
// L1 GEMM with gathered A rows: chunk row r -> x row (r/TC_)*T_ + t0 + r%TC_.
// K = IN_ = 24 (edge-handled). fp32 -> fp32, relu.
// ---------------------------------------------------------------------------
__global__ __launch_bounds__(256) void gemm_l1_gather(
    const float* __restrict__ x, const float* __restrict__ W,
    const float* __restrict__ bias, float* __restrict__ C, int t0)
{
  __shared__ float As[BKK][BM];
  __shared__ float Ws[BKK][BN];
  const int tid = threadIdx.x;
  const int m0 = blockIdx.x * BM;
  const int n0 = blockIdx.y * BN;
  const int lr = tid >> 2;
  const int kq = (tid & 3) << 2;
  const int ty = tid >> 4;
  const int tx = tid & 15;
  const int r = m0 + lr;
  const int b = r / TC_;
  const int tt = r - b * TC_;
  const size_t srow = (size_t)b * T_ + t0 + tt;
  float acc[4][4] = {};
  for (int k0 = 0; k0 < IN_; k0 += BKK) {
    {
      float v0 = 0.f, v1 = 0.f, v2 = 0.f, v3 = 0.f;
      const int kk = k0 + kq;
      const float* src = x + srow * IN_ + kk;
      if (kk + 4 <= IN_) {
        const float4 v = *(const float4*)src;
        v0 = v.x; v1 = v.y; v2 = v.z; v3 = v.w;
      } else {
        if (kk + 0 < IN_) v0 = src[0];
        if (kk + 1 < IN_) v1 = src[1];
        if (kk + 2 < IN_) v2 = src[2];
        if (kk + 3 < IN_) v3 = src[3];
      }
      As[kq + 0][lr] = v0; As[kq + 1][lr] = v1;
      As[kq + 2][lr] = v2; As[kq + 3][lr] = v3;
      float w0 = 0.f, w1 = 0.f, w2 = 0.f, w3 = 0.f;
      const float* srcw = W + (size_t)(n0 + lr) * IN_ + kk;
      if (kk + 4 <= IN_) {
        const float4 w = *(const float4*)srcw;
        w0 = w.x; w1 = w.y; w2 = w.z; w3 = w.w;
      } else {
        if (kk + 0 < IN_) w0 = srcw[0];
        if (kk + 1 < IN_) w1 = srcw[1];
        if (kk + 2 < IN_) w2 = srcw[2];
        if (kk + 3 < IN_) w3 = srcw[3];
      }
      Ws[kq + 0][lr] = w0; Ws[kq + 1][lr] = w1;
      Ws[kq + 2][lr] = w2; Ws[kq + 3][lr] = w3;
    }
    __syncthreads();
    #pragma unroll
    for (int k = 0; k < BKK; ++k) {
      const float4 av = *(const float4*)&As[k][ty << 2];
      const float4 bv = *(const float4*)&Ws[k][tx << 2];
      const float aa[4] = {av.x, av.y, av.z, av.w};
      const float bb[4] = {bv.x, bv.y, bv.z, bv.w};
      #pragma unroll
      for (int i = 0; i < 4; ++i)
        #pragma unroll
        for (int j = 0; j < 4; ++j)
          acc[i][j] = fmaf(aa[i], bb[j], acc[i][j]);
    }
    __syncthreads();
  }
  const float4 bvec = *(const float4*)&bias[n0 + (tx << 2)];
  const float bb[4] = {bvec.x, bvec.y, bvec.z, bvec.w};
  #pragma unroll
  for (int i = 0; i < 4; ++i) {
    float4 ov;
    ov.x = fmaxf(acc[i][0] + bb[0], 0.f);
    ov.y = fmaxf(acc[i][1] + bb[1], 0.f);
    ov.z = fmaxf(acc[i][2] + bb[2], 0.f);
    ov.w = fmaxf(acc[i][3] + bb[3], 0.f);
    *(float4*)&C[(size_t)(m0 + (ty << 2) + i) * H1_ + n0 + (tx << 2)] = ov;
  }
}

// Split-K partial of hg = h @ W_hh^T.  h: 64x2048 fp32; W_hh: 6144x2048 fp32.
__global__ __launch_bounds__(256) void gru_hg_partial(
    const float* __restrict__ h, const float* __restrict__ Whh,
    float* __restrict__ part)
{
  __shared__ float As[BKK][BM];
  __shared__ float Ws[BKK][BN];
  const int tid = threadIdx.x;
  const int n0 = blockIdx.x * BN;
  const int kbase = blockIdx.y * KC;
  const int lr = tid >> 2;
  const int kq = (tid & 3) << 2;
  const int ty = tid >> 4;
  const int tx = tid & 15;
  float acc[4][4] = {};
  for (int k0 = kbase; k0 < kbase + KC; k0 += BKK) {
    {
      const float4 v = *(const float4*)(h + (size_t)lr * HM_ + k0 + kq);
      As[kq + 0][lr] = v.x; As[kq + 1][lr] = v.y;
      As[kq + 2][lr] = v.z; As[kq + 3][lr] = v.w;
      const float4 w = *(const float4*)(Whh + (size_t)(n0 + lr) * HM_ + k0 + kq);
      Ws[kq + 0][lr] = w.x; Ws[kq + 1][lr] = w.y;
      Ws[kq + 2][lr] = w.z; Ws[kq + 3][lr] = w.w;
    }
    __syncthreads();
    #pragma unroll
    for (int k = 0; k < BKK; ++k) {
      const float4 av = *(const float4*)&As[k][ty << 2];
      const float4 bv = *(const float4*)&Ws[k][tx << 2];
      const float aa[4] = {av.x, av.y, av.z, av.w};
      const float bb[4] = {bv.x, bv.y, bv.z, bv.w};
      #pragma unroll
      for (int i = 0; i < 4; ++i)
        #pragma unroll
        for (int j = 0; j < 4; ++j)
          acc[i][j] = fmaf(aa[i], bb[j], acc[i][j]);
    }
    __syncthreads();
  }
  float* dst = part + (size_t)blockIdx.y * B_ * G3_;
  #pragma unroll
  for (int i = 0; i < 4; ++i) {
    float4 o = {acc[i][0], acc[i][1], acc[i][2], acc[i][3]};
    *(float4*)&dst[(size_t)((ty << 2) + i) * G3_ + n0 + (tx << 2)] = o;
  }
}

// Sum split-K partials + gate math. xg_c/hs_c are chunk-local: row = b*TC_+tt.
__global__ __launch_bounds__(256) void gru_gate(
    const float* __restrict__ part, const bf16_t* __restrict__ xg_c,
    const float* __restrict__ b_hh, float* __restrict__ h,
    bf16_t* __restrict__ hs_c, int tt)
{
  const int idx = blockIdx.x * 256 + threadIdx.x;  // 0..131071
  const int b = idx >> 11;
  const int j = idx & (HM_ - 1);
  float hr = 0.f, hz = 0.f, hn = 0.f;
  #pragma unroll
  for (int kc = 0; kc < 8; ++kc) {
    const float* p = part + ((size_t)kc * B_ + b) * G3_ + j;
    hr += p[0];
    hz += p[HM_];
    hn += p[2 * HM_];
  }
  hr += b_hh[j];
  hz += b_hh[HM_ + j];
  hn += b_hh[2 * HM_ + j];
  const size_t row = (size_t)(b * TC_ + tt);
  const bf16_t* xrow = xg_c + row * G3_ + j;
  const float xr = bf2f(xrow[0]);
  const float xz = bf2f(xrow[HM_]);
  const float xn = bf2f(xrow[2 * HM_]);
  const float r = 1.f / (1.f + expf(-(xr + hr)));
  const float z = 1.f / (1.f + expf(-(xz + hz)));
  const float n = tanhf(xn + r * hn);
  const float hp = h[idx];
  const float hnew = (1.f - z) * n + z * hp;
  h[idx] = hnew;
  hs_c[row * HM_ + j] = f2bf(hnew);
}

// Heads for one chunk. Block r in [0,MC): b=r/TC_, t=t0+r%TC_.
__global__ __launch_bounds__(256) void heads_kernel(
    const float* __restrict__ outs_c, const int* __restrict__ label,
    const float* __restrict__ W4, const float* __restrict__ b4,
    const float* __restrict__ W5, const float* __restrict__ b5,
    const float* __restrict__ W6, const float* __restrict__ b6,
    float* __restrict__ out, int t0)
{
  const int r = blockIdx.x;
  const int b = r / TC_;
  const int tt = r - b * TC_;
  int lab = label[b];
  lab = lab < 0 ? 0 : (lab > C_ - 1 ? C_ - 1 : lab);  // fault guard
  const int tid = threadIdx.x;
  const float* o  = outs_c + (size_t)r * PEN_;
  const float* w4 = W4 + (size_t)lab * PEN_;
  const float* w5 = W5 + (size_t)lab * PEN_;
  const float* w6 = W6 + (size_t)lab * PEN_;
  float s4 = 0.f, s5 = 0.f, s6 = 0.f;
  for (int p = tid; p < PEN_; p += 256) {
    const float ov = o[p];
    s4 = fmaf(ov, w4[p], s4);
    s5 = fmaf(ov, w5[p], s5);
    s6 = fmaf(ov, w6[p], s6);
  }
  #pragma unroll
  for (int off = 32; off > 0; off >>= 1) {
    s4 += __shfl_down(s4, off, 64);
    s5 += __shfl_down(s5, off, 64);
    s6 += __shfl_down(s6, off, 64);
  }
  __shared__ float red[4][3];
  const int wave = tid >> 6;
  if ((tid & 63) == 0) { red[wave][0] = s4; red[wave][1] = s5; red[wave][2] = s6; }
  __syncthreads();
  if (tid == 0) {
    const int bt = b * T_ + t0 + tt;
    out[bt]           = red[0][0] + red[1][0] + red[2][0] + red[3][0] + b4[lab];
    out[BT_ + bt]     = red[0][1] + red[1][1] + red[2][1] + red[3][1] + b5[lab];
    out[2 * BT_ + bt] = red[0][2] + red[1][2] + red[2][2] + red[3][2] + b6[lab];
    if (t0 == 0 && r == 0) { out[3 * BT_] = 0.f; out[3 * BT_ + 1] = 0.f; }
  }
}

__global__ __launch_bounds__(256) void zero_f(float* __restrict__ p, int n) {
  const int i = blockIdx.x * 256 + threadIdx.x;
  if (i < n) p[i] = 0.f;
}

extern "C" void kernel_launch(void* const* d_in, const int* in_sizes, int n_in,
                              void* d_out, int out_size, void* d_ws, size_t ws_size,
                              hipStream_t stream) {
  const float* x     = (const float*)d_in[0];
  const int*   label = (const int*)d_in[1];
  const float* W1    = (const float*)d_in[2];
  const float* b1    = (const float*)d_in[3];
  const float* W2    = (const float*)d_in[4];
  const float* b2    = (const float*)d_in[5];
  const float* W_ih  = (const float*)d_in[6];
  const float* W_hh  = (const float*)d_in[7];
  const float* b_ih  = (const float*)d_in[8];
  const float* b_hh  = (const float*)d_in[9];
  const float* W3    = (const float*)d_in[10];
  const float* b3    = (const float*)d_in[11];
  const float* W4    = (const float*)d_in[12];
  const float* b4    = (const float*)d_in[13];
  const float* W5    = (const float*)d_in[14];
  const float* b5    = (const float*)d_in[15];
  const float* W6    = (const float*)d_in[16];
  const float* b6    = (const float*)d_in[17];

  // Workspace layout (bytes), total 93,061,120 (~89 MB):
  //  [0,          47972352)  xg_c   bf16 (MC x 6144)
  //  [47972352,   63963136)  out2_c bf16 (MC x 2048)  -> reused as hs_c bf16 (MC x 2048)
  //  [63963136,   79953920)  out1_c fp32 (MC x 1024)  -> reused as outs_c fp32 (MC x 1024)
  //  [79953920,   92536832)  part   fp32 (8 x 64 x 6144)
  //  [92536832,   93061120)  h      fp32 (64 x 2048)
  const size_t NEEDED = 93061120UL;
  if (ws_size < NEEDED) return;  // diagnostic guard: clean absmax-fail, not a fault

  char* ws = (char*)d_ws;
  bf16_t* xg_c   = (bf16_t*)(ws + 0);
  bf16_t* out2_c = (bf16_t*)(ws + 47972352UL);
  bf16_t* hs_c   = out2_c;
  float*  out1_c = (float*)(ws + 63963136UL);
  float*  outs_c = out1_c;
  float*  part   = (float*)(ws + 79953920UL);
  float*  h      = (float*)(ws + 92536832UL);
  float*  out    = (float*)d_out;

  const dim3 blk(256);

  zero_f<<<dim3(B_ * HM_ / 256), blk, 0, stream>>>(h, B_ * HM_);

  for (int c = 0; c < NCH; ++c) {
    const int t0 = c * TC_;
    // Front MLP for this T-chunk (rows gathered from x).
    gemm_l1_gather<<<dim3(MC / BM, H1_ / BN), blk, 0, stream>>>(x, W1, b1, out1_c, t0);
    gemm_nt<float, bf16_t><<<dim3(MC / BM, H2_ / BN), blk, 0, stream>>>(
        out1_c, W2, b2, out2_c, MC, H2_, H1_, 1);
    gemm_nt<bf16_t, bf16_t><<<dim3(MC / BM, G3_ / BN), blk, 0, stream>>>(
        out2_c, W_ih, b_ih, xg_c, MC, G3_, H2_, 0);
    // GRU scan over this chunk (hs_c overwrites out2_c region — out2 is dead).
    for (int tt = 0; tt < TC_; ++tt) {
      gru_hg_partial<<<dim3(G3_ / BN, HM_ / KC), blk, 0, stream>>>(h, W_hh, part);
      gru_gate<<<dim3(B_ * HM_ / 256), blk, 0, stream>>>(part, xg_c, b_hh, h, hs_c, tt);
    }
    // Tail: out_s chunk (into out1_c region) + heads.
    gemm_nt<bf16_t, float><<<dim3(MC / BM, PEN_ / BN), blk, 0, stream>>>(
        hs_c, W3, b3, outs_c, MC, PEN_, HM_, 1);
    heads_kernel<<<dim3(MC), blk, 0, stream>>>(
        outs_c, label, W4, b4, W5, b5, W6, b6, out, t0);
  }
}

// Round 5
// 12865.184 us; speedup vs baseline: 1.7974x; 1.7974x over previous
//
#include <hip/hip_runtime.h>
#include <math.h>

#define B_   64
#define T_   366
#define IN_  24
#define H1_  1024
#define H2_  2048
#define HM_  2048
#define G3_  (3 * HM_)
#define PEN_ 1024
#define C_   21
#define BT_  (B_ * T_)

#define TC_  61              // T-chunk length (366 = 6*61)
#define NCH  6
#define MC   (B_ * TC_)      // 3904 rows per chunk

typedef unsigned short bf16_t;
typedef __bf16 bf16x8 __attribute__((ext_vector_type(8)));
typedef float  f32x4  __attribute__((ext_vector_type(4)));

__device__ __forceinline__ float bf2f(bf16_t u) {
  return __uint_as_float(((unsigned int)u) << 16);
}
__device__ __forceinline__ bf16_t f2bf(float f) {
  unsigned int x = __float_as_uint(f);
  unsigned int r = (x + 0x7fffu + ((x >> 16) & 1u)) >> 16;
  return (bf16_t)r;
}

struct ushort4_t { bf16_t x, y, z, w; };

// ---------------------------------------------------------------------------
// MFMA bf16 GEMM: C[m,n] = act(sum_k A[m,k]*W[n,k] + bias[n]),  C bf16.
// A: MxK bf16 row-major. W: NxK fp32 row-major (converted in staging).
// Tile 128x128, BK=32, 4 waves (2x2 of 64x64), mfma_f32_16x16x32_bf16.
// LDS row stride 40 elems (pad +8) -> frag b128 reads are 2-way (free).
// N must be a multiple of 128; M-edge handled by clamp+skip.
// ---------------------------------------------------------------------------
#define GBM 128
#define GBN 128
#define GBK 32
#define LDT 40

__global__ __launch_bounds__(256) void gemm_mfma(
    const bf16_t* __restrict__ A, const float* __restrict__ W,
    const float* __restrict__ bias, bf16_t* __restrict__ C,
    int M, int N, int K, int relu)
{
  __shared__ bf16_t Asl[GBM * LDT];
  __shared__ bf16_t Wsl[GBN * LDT];
  const int tid  = threadIdx.x;
  const int m0   = blockIdx.x * GBM;
  const int n0   = blockIdx.y * GBN;
  const int wave = tid >> 6;
  const int lane = tid & 63;
  const int l16  = lane & 15;
  const int quad = lane >> 4;
  const int wm   = (wave & 1) * 64;
  const int wn   = (wave >> 1) * 64;
  // staging coords: each thread loads one 16-elem segment of one row
  const int srow = tid >> 1;
  const int sseg = (tid & 1) << 4;
  const int arow = (m0 + srow < M) ? (m0 + srow) : (M - 1);

  f32x4 acc[4][4];
  #pragma unroll
  for (int i = 0; i < 4; ++i)
    #pragma unroll
    for (int j = 0; j < 4; ++j)
      acc[i][j] = (f32x4){0.f, 0.f, 0.f, 0.f};

  for (int k0 = 0; k0 < K; k0 += GBK) {
    {
      const bf16_t* ga = A + (size_t)arow * K + k0 + sseg;
      const uint4 a0 = *(const uint4*)ga;
      const uint4 a1 = *(const uint4*)(ga + 8);
      *(uint4*)&Asl[srow * LDT + sseg]     = a0;
      *(uint4*)&Asl[srow * LDT + sseg + 8] = a1;
      const float* gw = W + (size_t)(n0 + srow) * K + k0 + sseg;
      const float4 w0 = *(const float4*)gw;
      const float4 w1 = *(const float4*)(gw + 4);
      const float4 w2 = *(const float4*)(gw + 8);
      const float4 w3 = *(const float4*)(gw + 12);
      ushort4_t p0 = {f2bf(w0.x), f2bf(w0.y), f2bf(w0.z), f2bf(w0.w)};
      ushort4_t p1 = {f2bf(w1.x), f2bf(w1.y), f2bf(w1.z), f2bf(w1.w)};
      ushort4_t p2 = {f2bf(w2.x), f2bf(w2.y), f2bf(w2.z), f2bf(w2.w)};
      ushort4_t p3 = {f2bf(w3.x), f2bf(w3.y), f2bf(w3.z), f2bf(w3.w)};
      *(ushort4_t*)&Wsl[srow * LDT + sseg]      = p0;
      *(ushort4_t*)&Wsl[srow * LDT + sseg + 4]  = p1;
      *(ushort4_t*)&Wsl[srow * LDT + sseg + 8]  = p2;
      *(ushort4_t*)&Wsl[srow * LDT + sseg + 12] = p3;
    }
    __syncthreads();
    bf16x8 af[4], bf[4];
    #pragma unroll
    for (int i = 0; i < 4; ++i)
      af[i] = *(const bf16x8*)&Asl[(wm + 16 * i + l16) * LDT + quad * 8];
    #pragma unroll
    for (int j = 0; j < 4; ++j)
      bf[j] = *(const bf16x8*)&Wsl[(wn + 16 * j + l16) * LDT + quad * 8];
    #pragma unroll
    for (int i = 0; i < 4; ++i)
      #pragma unroll
      for (int j = 0; j < 4; ++j)
        acc[i][j] = __builtin_amdgcn_mfma_f32_16x16x32_bf16(af[i], bf[j], acc[i][j], 0, 0, 0);
    __syncthreads();
  }

  // epilogue: D row m = wm+16i+quad*4+reg, col n = wn+16j+l16
  #pragma unroll
  for (int j = 0; j < 4; ++j) {
    const int n = n0 + wn + 16 * j + l16;
    const float bn = bias[n];
    #pragma unroll
    for (int i = 0; i < 4; ++i) {
      #pragma unroll
      for (int reg = 0; reg < 4; ++reg) {
        const int m = m0 + wm + 16 * i + quad * 4 + reg;
        if (m < M) {
          float v = acc[i][j][reg] + bn;
          if (relu) v = fmaxf(v, 0.f);
          C[(size_t)m * N + n] = f2bf(v);
        }
      }
    }
  }
}

// ---------------------------------------------------------------------------
// Fused GRU step (one launch per t): 128 wgs x 256 thr.
// wg owns j0..j0+15 (j0 = blockIdx.x*16); computes hg for gates r,z,n over
// all 64 batch rows with K=2048 (MFMA, weights/h staged in LDS), then gate
// math + h update in-register. h_bf ping-pong avoids intra-launch races;
// h_f (fp32 master) is owner-only read/write, safe in place.
// ---------------------------------------------------------------------------
#define HLD 72   // padded LDS stride for 64-k tiles

__global__ __launch_bounds__(256) void gru_step(
    const bf16_t* __restrict__ h_bf_in, float* __restrict__ h_f,
    const bf16_t* __restrict__ Whh_bf, const bf16_t* __restrict__ xg_c,
    const float* __restrict__ b_hh,
    bf16_t* __restrict__ h_bf_out, bf16_t* __restrict__ hs_c, int tt)
{
  __shared__ bf16_t hst[64 * HLD];
  __shared__ bf16_t wst[48 * HLD];
  const int tid  = threadIdx.x;
  const int wave = tid >> 6;
  const int lane = tid & 63;
  const int l16  = lane & 15;
  const int quad = lane >> 4;
  const int j0   = blockIdx.x * 16;

  f32x4 acc[3];
  acc[0] = (f32x4){0.f, 0.f, 0.f, 0.f};
  acc[1] = acc[0];
  acc[2] = acc[0];

  const int hrow = tid >> 2;
  const int hseg = (tid & 3) << 4;
  const int wrow = tid >> 2;            // valid for tid<192
  const int wg   = wrow >> 4;           // gate index
  const int wjr  = wrow & 15;

  for (int k0 = 0; k0 < HM_; k0 += 64) {
    {
      const bf16_t* gh = h_bf_in + (size_t)hrow * HM_ + k0 + hseg;
      const uint4 h0 = *(const uint4*)gh;
      const uint4 h1 = *(const uint4*)(gh + 8);
      *(uint4*)&hst[hrow * HLD + hseg]     = h0;
      *(uint4*)&hst[hrow * HLD + hseg + 8] = h1;
      if (tid < 192) {
        const bf16_t* gw = Whh_bf + (size_t)(wg * HM_ + j0 + wjr) * HM_ + k0 + hseg;
        const uint4 w0 = *(const uint4*)gw;
        const uint4 w1 = *(const uint4*)(gw + 8);
        *(uint4*)&wst[wrow * HLD + hseg]     = w0;
        *(uint4*)&wst[wrow * HLD + hseg + 8] = w1;
      }
    }
    __syncthreads();
    #pragma unroll
    for (int s = 0; s < 2; ++s) {
      const bf16x8 afr = *(const bf16x8*)&hst[(wave * 16 + l16) * HLD + s * 32 + quad * 8];
      #pragma unroll
      for (int g = 0; g < 3; ++g) {
        const bf16x8 bfr = *(const bf16x8*)&wst[(g * 16 + l16) * HLD + s * 32 + quad * 8];
        acc[g] = __builtin_amdgcn_mfma_f32_16x16x32_bf16(afr, bfr, acc[g], 0, 0, 0);
      }
    }
    __syncthreads();
  }

  const int j = j0 + l16;
  const float bh_r = b_hh[j];
  const float bh_z = b_hh[HM_ + j];
  const float bh_n = b_hh[2 * HM_ + j];
  #pragma unroll
  for (int reg = 0; reg < 4; ++reg) {
    const int b = wave * 16 + quad * 4 + reg;
    const size_t xrow = (size_t)(b * TC_ + tt) * G3_;
    const float xr = bf2f(xg_c[xrow + j]);
    const float xz = bf2f(xg_c[xrow + HM_ + j]);
    const float xn = bf2f(xg_c[xrow + 2 * HM_ + j]);
    const float r = 1.f / (1.f + expf(-(xr + acc[0][reg] + bh_r)));
    const float z = 1.f / (1.f + expf(-(xz + acc[1][reg] + bh_z)));
    const float n = tanhf(xn + r * (acc[2][reg] + bh_n));
    const float hp = h_f[b * HM_ + j];
    const float hnew = (1.f - z) * n + z * hp;
    h_f[b * HM_ + j] = hnew;
    const bf16_t hb = f2bf(hnew);
    h_bf_out[b * HM_ + j] = hb;
    hs_c[(size_t)(b * TC_ + tt) * HM_ + j] = hb;
  }
}

// ---------------------------------------------------------------------------
// L1 GEMM with gathered rows (K=24, fp32 vector math), bf16 output.
// ---------------------------------------------------------------------------
#define BM 64
#define BN 64
#define BKK 16

__global__ __launch_bounds__(256) void gemm_l1_gather(
    const float* __restrict__ x, const float* __restrict__ W,
    const float* __restrict__ bias, bf16_t* __restrict__ C, int t0)
{
  __shared__ float As[BKK][BM];
  __shared__ float Ws[BKK][BN];
  const int tid = threadIdx.x;
  const int m0 = blockIdx.x * BM;
  const int n0 = blockIdx.y * BN;
  const int lr = tid >> 2;
  const int kq = (tid & 3) << 2;
  const int ty = tid >> 4;
  const int tx = tid & 15;
  const int r = m0 + lr;
  const int b = r / TC_;
  const int tt = r - b * TC_;
  const size_t srow = (size_t)b * T_ + t0 + tt;
  float acc[4][4] = {};
  for (int k0 = 0; k0 < IN_; k0 += BKK) {
    {
      float v0 = 0.f, v1 = 0.f, v2 = 0.f, v3 = 0.f;
      const int kk = k0 + kq;
      const float* src = x + srow * IN_ + kk;
      if (kk + 4 <= IN_) {
        const float4 v = *(const float4*)src;
        v0 = v.x; v1 = v.y; v2 = v.z; v3 = v.w;
      }
      As[kq + 0][lr] = v0; As[kq + 1][lr] = v1;
      As[kq + 2][lr] = v2; As[kq + 3][lr] = v3;
      float w0 = 0.f, w1 = 0.f, w2 = 0.f, w3 = 0.f;
      const float* srcw = W + (size_t)(n0 + lr) * IN_ + kk;
      if (kk + 4 <= IN_) {
        const float4 w = *(const float4*)srcw;
        w0 = w.x; w1 = w.y; w2 = w.z; w3 = w.w;
      }
      Ws[kq + 0][lr] = w0; Ws[kq + 1][lr] = w1;
      Ws[kq + 2][lr] = w2; Ws[kq + 3][lr] = w3;
    }
    __syncthreads();
    #pragma unroll
    for (int k = 0; k < BKK; ++k) {
      const float4 av = *(const float4*)&As[k][ty << 2];
      const float4 bv = *(const float4*)&Ws[k][tx << 2];
      const float aa[4] = {av.x, av.y, av.z, av.w};
      const float bb[4] = {bv.x, bv.y, bv.z, bv.w};
      #pragma unroll
      for (int i = 0; i < 4; ++i)
        #pragma unroll
        for (int j = 0; j < 4; ++j)
          acc[i][j] = fmaf(aa[i], bb[j], acc[i][j]);
    }
    __syncthreads();
  }
  const float4 bvec = *(const float4*)&bias[n0 + (tx << 2)];
  const float bb[4] = {bvec.x, bvec.y, bvec.z, bvec.w};
  #pragma unroll
  for (int i = 0; i < 4; ++i) {
    ushort4_t ov;
    ov.x = f2bf(fmaxf(acc[i][0] + bb[0], 0.f));
    ov.y = f2bf(fmaxf(acc[i][1] + bb[1], 0.f));
    ov.z = f2bf(fmaxf(acc[i][2] + bb[2], 0.f));
    ov.w = f2bf(fmaxf(acc[i][3] + bb[3], 0.f));
    *(ushort4_t*)&C[(size_t)(m0 + (ty << 2) + i) * H1_ + n0 + (tx << 2)] = ov;
  }
}

// Heads for one chunk (outs bf16). Block r: b=r/TC_, t=t0+r%TC_.
__global__ __launch_bounds__(256) void heads_kernel(
    const bf16_t* __restrict__ outs_c, const int* __restrict__ label,
    const float* __restrict__ W4, const float* __restrict__ b4,
    const float* __restrict__ W5, const float* __restrict__ b5,
    const float* __restrict__ W6, const float* __restrict__ b6,
    float* __restrict__ out, int t0)
{
  const int r = blockIdx.x;
  const int b = r / TC_;
  const int tt = r - b * TC_;
  int lab = label[b];
  lab = lab < 0 ? 0 : (lab > C_ - 1 ? C_ - 1 : lab);
  const int tid = threadIdx.x;
  const bf16_t* o = outs_c + (size_t)r * PEN_;
  const float* w4 = W4 + (size_t)lab * PEN_;
  const float* w5 = W5 + (size_t)lab * PEN_;
  const float* w6 = W6 + (size_t)lab * PEN_;
  float s4 = 0.f, s5 = 0.f, s6 = 0.f;
  for (int p = tid; p < PEN_; p += 256) {
    const float ov = bf2f(o[p]);
    s4 = fmaf(ov, w4[p], s4);
    s5 = fmaf(ov, w5[p], s5);
    s6 = fmaf(ov, w6[p], s6);
  }
  #pragma unroll
  for (int off = 32; off > 0; off >>= 1) {
    s4 += __shfl_down(s4, off, 64);
    s5 += __shfl_down(s5, off, 64);
    s6 += __shfl_down(s6, off, 64);
  }
  __shared__ float red[4][3];
  const int wave = tid >> 6;
  if ((tid & 63) == 0) { red[wave][0] = s4; red[wave][1] = s5; red[wave][2] = s6; }
  __syncthreads();
  if (tid == 0) {
    const int bt = b * T_ + t0 + tt;
    out[bt]           = red[0][0] + red[1][0] + red[2][0] + red[3][0] + b4[lab];
    out[BT_ + bt]     = red[0][1] + red[1][1] + red[2][1] + red[3][1] + b5[lab];
    out[2 * BT_ + bt] = red[0][2] + red[1][2] + red[2][2] + red[3][2] + b6[lab];
    if (t0 == 0 && r == 0) { out[3 * BT_] = 0.f; out[3 * BT_ + 1] = 0.f; }
  }
}

__global__ __launch_bounds__(256) void cvt_bf(const float* __restrict__ src,
                                              bf16_t* __restrict__ dst, int n) {
  const int i = (blockIdx.x * 256 + threadIdx.x) * 4;
  if (i + 4 <= n) {
    const float4 v = *(const float4*)&src[i];
    ushort4_t o = {f2bf(v.x), f2bf(v.y), f2bf(v.z), f2bf(v.w)};
    *(ushort4_t*)&dst[i] = o;
  }
}

__global__ __launch_bounds__(256) void zero_h(float* __restrict__ hf,
                                              bf16_t* __restrict__ hb0,
                                              bf16_t* __restrict__ hb1) {
  const int i = blockIdx.x * 256 + threadIdx.x;  // 131072
  hf[i] = 0.f; hb0[i] = 0; hb1[i] = 0;
}

extern "C" void kernel_launch(void* const* d_in, const int* in_sizes, int n_in,
                              void* d_out, int out_size, void* d_ws, size_t ws_size,
                              hipStream_t stream) {
  const float* x     = (const float*)d_in[0];
  const int*   label = (const int*)d_in[1];
  const float* W1    = (const float*)d_in[2];
  const float* b1    = (const float*)d_in[3];
  const float* W2    = (const float*)d_in[4];
  const float* b2    = (const float*)d_in[5];
  const float* W_ih  = (const float*)d_in[6];
  const float* W_hh  = (const float*)d_in[7];
  const float* b_ih  = (const float*)d_in[8];
  const float* b_hh  = (const float*)d_in[9];
  const float* W3    = (const float*)d_in[10];
  const float* b3    = (const float*)d_in[11];
  const float* W4    = (const float*)d_in[12];
  const float* b4    = (const float*)d_in[13];
  const float* W5    = (const float*)d_in[14];
  const float* b5    = (const float*)d_in[15];
  const float* W6    = (const float*)d_in[16];
  const float* b6    = (const float*)d_in[17];

  // Workspace layout (bytes), total 98,172,928 (~94 MB):
  //  [0,          47972352)  xg_c    bf16 (MC x 6144)
  //  [47972352,   63963136)  out2_c  bf16 (MC x 2048)  = hs_c after xg GEMM
  //  [63963136,   71958528)  out1_c  bf16 (MC x 1024)  = outs_c after scan
  //  [71958528,   97124352)  Whh_bf  bf16 (6144 x 2048)
  //  [97124352,   97648640)  h_f     fp32 (64 x 2048)
  //  [97648640,   97910784)  h_bf0   bf16 (64 x 2048)
  //  [97910784,   98172928)  h_bf1   bf16 (64 x 2048)
  const size_t NEEDED = 98172928UL;
  if (ws_size < NEEDED) return;  // clean absmax-fail, not a fault

  char* ws = (char*)d_ws;
  bf16_t* xg_c   = (bf16_t*)(ws + 0);
  bf16_t* out2_c = (bf16_t*)(ws + 47972352UL);
  bf16_t* hs_c   = out2_c;
  bf16_t* out1_c = (bf16_t*)(ws + 63963136UL);
  bf16_t* outs_c = out1_c;
  bf16_t* Whh_bf = (bf16_t*)(ws + 71958528UL);
  float*  h_f    = (float*)(ws + 97124352UL);
  bf16_t* h_bf[2];
  h_bf[0] = (bf16_t*)(ws + 97648640UL);
  h_bf[1] = (bf16_t*)(ws + 97910784UL);
  float* out = (float*)d_out;

  const dim3 blk(256);

  cvt_bf<<<dim3(G3_ * HM_ / 1024), blk, 0, stream>>>(W_hh, Whh_bf, G3_ * HM_);
  zero_h<<<dim3(B_ * HM_ / 256), blk, 0, stream>>>(h_f, h_bf[0], h_bf[1]);

  int pp = 0;
  for (int c = 0; c < NCH; ++c) {
    const int t0 = c * TC_;
    gemm_l1_gather<<<dim3(MC / BM, H1_ / BN), blk, 0, stream>>>(x, W1, b1, out1_c, t0);
    gemm_mfma<<<dim3((MC + GBM - 1) / GBM, H2_ / GBN), blk, 0, stream>>>(
        out1_c, W2, b2, out2_c, MC, H2_, H1_, 1);
    gemm_mfma<<<dim3((MC + GBM - 1) / GBM, G3_ / GBN), blk, 0, stream>>>(
        out2_c, W_ih, b_ih, xg_c, MC, G3_, H2_, 0);
    for (int tt = 0; tt < TC_; ++tt) {
      gru_step<<<dim3(HM_ / 16), blk, 0, stream>>>(
          h_bf[pp], h_f, Whh_bf, xg_c, b_hh, h_bf[1 - pp], hs_c, tt);
      pp = 1 - pp;
    }
    gemm_mfma<<<dim3((MC + GBM - 1) / GBM, PEN_ / GBN), blk, 0, stream>>>(
        hs_c, W3, b3, outs_c, MC, PEN_, HM_, 1);
    heads_kernel<<<dim3(MC), blk, 0, stream>>>(
        outs_c, label, W4, b4, W5, b5, W6, b6, out, t0);
  }
}